// Round 6
// baseline (292.661 us; speedup 1.0000x reference)
//
#include <hip/hip_runtime.h>

#define R_DIM 1024
#define N_DIM 1024
#define FEAT  1024
#define EMB   64
#define GROUP 16
#define DG    64

typedef _Float16 half8  __attribute__((ext_vector_type(8)));
typedef _Float16 half4v __attribute__((ext_vector_type(4)));
typedef float    f32x4  __attribute__((ext_vector_type(4)));

__device__ __forceinline__ half8 cvt8(const float* p) {
  const float4 a = *(const float4*)p;
  const float4 b = *(const float4*)(p + 4);
  half8 h;
  h[0] = (_Float16)a.x; h[1] = (_Float16)a.y; h[2] = (_Float16)a.z; h[3] = (_Float16)a.w;
  h[4] = (_Float16)b.x; h[5] = (_Float16)b.y; h[6] = (_Float16)b.z; h[7] = (_Float16)b.w;
  return h;
}

// ---------------------------------------------------------------------------
// Fused producer kernel. Role by blockIdx.x:
//   [0,256)    q  = f16(roi @ Wq^T + bq)        -> qh  [r][f]
//   [256,512)  k  = f16(roi @ Wk^T + bk)        -> kh  [r][f]
//   [512,768)  kc = f16(Wc[g] @ roi^T)          -> kct [g][o][n]
//   [768,2816) pos: logw[r,g,n] = log(max(pe[r,n,:].Wp[g,:]+bp[g], 1e-6)) f16
// GEMM path: 64x64 tile, 4 waves (16 rows each x 4 col-tiles), MFMA f16 with
// fp32->f16 cvt in registers, K=1024 in 32-chunks. Fragment maps identical to
// the HW-validated attn kernel. pos path: wave=16 rows, 4 lanes/row owning a
// 16-float e-chunk; Wp broadcast from padded LDS (l4 stride 264 dwords ->
// banks 0/8/16/24, conflict-free); butterfly reduce over shfl_xor 1,2.
// ---------------------------------------------------------------------------
__global__ __launch_bounds__(256) void producers(
    const float* __restrict__ roi, const float* __restrict__ Wq,
    const float* __restrict__ bq,  const float* __restrict__ Wk,
    const float* __restrict__ bk,  const float* __restrict__ Wc,
    const float* __restrict__ pe,  const float* __restrict__ Wp,
    const float* __restrict__ bp,
    _Float16* __restrict__ qh, _Float16* __restrict__ kh,
    _Float16* __restrict__ kct, _Float16* __restrict__ logw)
{
  __shared__ float lds_w[4 * 264];   // 4.2 KB, only the pos role uses it
  const int bx = blockIdx.x;
  const int t  = threadIdx.x;

  if (bx < 768) {
    // ---------------- GEMM role ----------------
    const float* A; const float* B; const float* bias;
    _Float16* outb; int r0, c0;
    if (bx < 256) {
      A = roi; B = Wq; bias = bq; outb = qh;
      r0 = (bx >> 4) << 6; c0 = (bx & 15) << 6;
    } else if (bx < 512) {
      const int i = bx - 256;
      A = roi; B = Wk; bias = bk; outb = kh;
      r0 = (i >> 4) << 6; c0 = (i & 15) << 6;
    } else {
      const int i = bx - 512, g = i >> 4;
      A = Wc + ((size_t)g << 16); B = roi; bias = nullptr;
      outb = kct + ((size_t)g << 16);
      r0 = 0; c0 = (i & 15) << 6;
    }
    const int wv = t >> 6, l = t & 63, q16 = l & 15, q4 = l >> 4;
    const float* ap  = A + (size_t)(r0 + (wv << 4) + q16) * FEAT + (q4 << 3);
    const float* bp0 = B + (size_t)(c0 + q16) * FEAT + (q4 << 3);

    f32x4 acc[4];
#pragma unroll
    for (int ct = 0; ct < 4; ++ct) acc[ct] = (f32x4){0.f, 0.f, 0.f, 0.f};

    for (int kk = 0; kk < FEAT; kk += 32) {
      const half8 a = cvt8(ap + kk);
#pragma unroll
      for (int ct = 0; ct < 4; ++ct) {
        const half8 b = cvt8(bp0 + (size_t)(ct << 4) * FEAT + kk);
        acc[ct] = __builtin_amdgcn_mfma_f32_16x16x32_f16(a, b, acc[ct], 0, 0, 0);
      }
    }
#pragma unroll
    for (int ct = 0; ct < 4; ++ct) {
      const int col = c0 + (ct << 4) + q16;
      const float bv = bias ? bias[col] : 0.f;
#pragma unroll
      for (int j = 0; j < 4; ++j) {
        const int row = r0 + (wv << 4) + (q4 << 2) + j;
        outb[(size_t)row * FEAT + col] = (_Float16)(acc[ct][j] + bv);
      }
    }
  } else {
    // ---------------- pos role ----------------
    {  // stage WpT: lds_w[l4][i][g] = Wp[g][l4*16+i], l4-stride 264 dwords
      const float4 v = ((const float4*)Wp)[t];
      const int l4s = (t & 15) >> 2, ib = (t & 3) << 2, g = t >> 4;
#pragma unroll
      for (int c = 0; c < 4; ++c)
        lds_w[l4s * 264 + (ib + c) * 16 + g] = ((const float*)&v)[c];
    }
    __syncthreads();
    const int w = t >> 6, l = t & 63, r16 = l >> 2, l4 = l & 3;
    const float4 bpv = *(const float4*)(bp + (l4 << 2));
    const int pb = bx - 768;
#pragma unroll 1
    for (int it = 0; it < 8; ++it) {
      const int rowb = ((pb << 5) + (w << 3) + it) << 4;
      const int row  = rowb + r16;
      const float* src = pe + ((size_t)row << 6) + (l4 << 4);
      float x[16];
      *(float4*)&x[0]  = *(const float4*)(src);
      *(float4*)&x[4]  = *(const float4*)(src + 4);
      *(float4*)&x[8]  = *(const float4*)(src + 8);
      *(float4*)&x[12] = *(const float4*)(src + 12);
      float acc[16];
#pragma unroll
      for (int g = 0; g < 16; ++g) acc[g] = 0.f;
#pragma unroll
      for (int i = 0; i < 16; ++i) {
#pragma unroll
        for (int g4 = 0; g4 < 4; ++g4) {
          const float4 w4 = *(const float4*)&lds_w[l4 * 264 + i * 16 + (g4 << 2)];
          acc[(g4 << 2) + 0] += x[i] * w4.x;
          acc[(g4 << 2) + 1] += x[i] * w4.y;
          acc[(g4 << 2) + 2] += x[i] * w4.z;
          acc[(g4 << 2) + 3] += x[i] * w4.w;
        }
      }
#pragma unroll
      for (int g = 0; g < 16; ++g) {
        acc[g] += __shfl_xor(acc[g], 1);
        acc[g] += __shfl_xor(acc[g], 2);
      }
      const int r = row >> 10, n = row & 1023;
      _Float16* dst = logw + ((size_t)(r << 4) << 10) + n;
#pragma unroll
      for (int c = 0; c < 4; ++c) {
        const int g = (l4 << 2) + c;
        const float v = fmaxf(acc[g] + ((const float*)&bpv)[c], 1e-6f);
        dst[(size_t)g << 10] = (_Float16)__logf(v);
      }
    }
  }
}

// ---------------------------------------------------------------------------
// K4: MFMA attention (unchanged from R5). Block = 16 q-rows x one g, 4 waves.
// ---------------------------------------------------------------------------
#define PLD 1032
__global__ __launch_bounds__(256) void attn_mfma(
    const _Float16* __restrict__ qh, const _Float16* __restrict__ kh,
    const _Float16* __restrict__ logw, const _Float16* __restrict__ kct,
    const float* __restrict__ bc, float* __restrict__ outp)
{
  __shared__ __align__(16) _Float16 P[16][PLD];   // 33,024 B
  __shared__ float Ored[4][16][68];               // 17,408 B
  __shared__ float redm[4][16];
  __shared__ float redl[4][16];

  const int t   = threadIdx.x;
  const int w   = t >> 6;
  const int l   = t & 63;
  const int q16 = l & 15;
  const int q4  = l >> 4;
  const int g   = blockIdx.y;
  const int r0  = blockIdx.x << 4;
  const int nbase = w << 8;

  const half8* qp = (const half8*)(qh + (size_t)(r0 + q16) * FEAT + (g << 6) + (q4 << 3));
  const half8 a0 = qp[0];
  const half8 a1 = qp[4];

  f32x4 S[16];
#pragma unroll
  for (int i = 0; i < 16; ++i) S[i] = (f32x4){0.f, 0.f, 0.f, 0.f};
#pragma unroll
  for (int t16 = 0; t16 < 16; ++t16) {
    const int n0 = nbase + (t16 << 4);
    const half8* kp = (const half8*)(kh + (size_t)(n0 + q16) * FEAT + (g << 6) + (q4 << 3));
    S[t16] = __builtin_amdgcn_mfma_f32_16x16x32_f16(a0, kp[0], S[t16], 0, 0, 0);
    S[t16] = __builtin_amdgcn_mfma_f32_16x16x32_f16(a1, kp[4], S[t16], 0, 0, 0);
  }

#pragma unroll
  for (int t16 = 0; t16 < 16; ++t16) {
    const int n = nbase + (t16 << 4) + q16;
#pragma unroll
    for (int j = 0; j < 4; ++j) {
      const int r = r0 + (q4 << 2) + j;
      const float lw = (float)logw[(size_t)(((r << 4) + g) << 10) + n];
      S[t16][j] = S[t16][j] * 0.125f + lw;
    }
  }

  float m[4] = {-1e30f, -1e30f, -1e30f, -1e30f};
#pragma unroll
  for (int t16 = 0; t16 < 16; ++t16)
#pragma unroll
    for (int j = 0; j < 4; ++j) m[j] = fmaxf(m[j], S[t16][j]);
#pragma unroll
  for (int off = 8; off; off >>= 1)
#pragma unroll
    for (int j = 0; j < 4; ++j) m[j] = fmaxf(m[j], __shfl_xor(m[j], off));
  if (q16 == 0) {
#pragma unroll
    for (int j = 0; j < 4; ++j) redm[w][(q4 << 2) + j] = m[j];
  }
  __syncthreads();
#pragma unroll
  for (int j = 0; j < 4; ++j) {
    const int r = (q4 << 2) + j;
    m[j] = fmaxf(fmaxf(redm[0][r], redm[1][r]), fmaxf(redm[2][r], redm[3][r]));
  }

  float ls[4] = {0.f, 0.f, 0.f, 0.f};
#pragma unroll
  for (int t16 = 0; t16 < 16; ++t16) {
    const int n = nbase + (t16 << 4) + q16;
#pragma unroll
    for (int j = 0; j < 4; ++j) {
      const float p = __expf(S[t16][j] - m[j]);
      ls[j] += p;
      P[(q4 << 2) + j][n] = (_Float16)p;
    }
  }
#pragma unroll
  for (int off = 8; off; off >>= 1)
#pragma unroll
    for (int j = 0; j < 4; ++j) ls[j] += __shfl_xor(ls[j], off);
  if (q16 == 0) {
#pragma unroll
    for (int j = 0; j < 4; ++j) redl[w][(q4 << 2) + j] = ls[j];
  }
  __syncthreads();

  f32x4 O[4];
#pragma unroll
  for (int ot = 0; ot < 4; ++ot) O[ot] = (f32x4){0.f, 0.f, 0.f, 0.f};
#pragma unroll
  for (int ks = 0; ks < 8; ++ks) {
    const int nk = nbase + (ks << 5) + (q4 << 3);
    const half8 pa = *(const half8*)&P[q16][nk];
#pragma unroll
    for (int ot = 0; ot < 4; ++ot) {
      const half8 bfr = *(const half8*)(kct + (size_t)((g << 6) + (ot << 4) + q16) * N_DIM + nk);
      O[ot] = __builtin_amdgcn_mfma_f32_16x16x32_f16(pa, bfr, O[ot], 0, 0, 0);
    }
  }
#pragma unroll
  for (int ot = 0; ot < 4; ++ot)
#pragma unroll
    for (int j = 0; j < 4; ++j)
      Ored[w][(q4 << 2) + j][(ot << 4) + q16] = O[ot][j];
  __syncthreads();

  const int r  = t >> 4;
  const int o0 = (t & 15) << 2;
  const float lsum = redl[0][r] + redl[1][r] + redl[2][r] + redl[3][r];
  const float inv  = 1.0f / lsum;
  float o[4];
#pragma unroll
  for (int c = 0; c < 4; ++c)
    o[c] = Ored[0][r][o0 + c] + Ored[1][r][o0 + c] + Ored[2][r][o0 + c] + Ored[3][r][o0 + c];
  const float4 bcv = *(const float4*)(bc + (g << 6) + o0);
  float4 res;
  res.x = o[0] * inv + bcv.x;
  res.y = o[1] * inv + bcv.y;
  res.z = o[2] * inv + bcv.z;
  res.w = o[3] * inv + bcv.w;
  *(float4*)(outp + (size_t)(r0 + r) * FEAT + (g << 6) + o0) = res;
}

// ---------------------------------------------------------------------------
extern "C" void kernel_launch(void* const* d_in, const int* in_sizes, int n_in,
                              void* d_out, int out_size, void* d_ws, size_t ws_size,
                              hipStream_t stream)
{
  const float* pe  = (const float*)d_in[0];
  const float* roi = (const float*)d_in[1];
  const float* Wq  = (const float*)d_in[2];
  const float* bq  = (const float*)d_in[3];
  const float* Wk  = (const float*)d_in[4];
  const float* bk  = (const float*)d_in[5];
  const float* Wp  = (const float*)d_in[6];
  const float* bp  = (const float*)d_in[7];
  const float* Wc  = (const float*)d_in[8];
  const float* bc  = (const float*)d_in[9];
  float* outp = (float*)d_out;

  char* ws = (char*)d_ws;
  _Float16* qh   = (_Float16*)(ws);                        // 2 MB
  _Float16* kh   = (_Float16*)(ws + ((size_t)2 << 20));    // 2 MB
  _Float16* kct  = (_Float16*)(ws + ((size_t)4 << 20));    // 2 MB [g][o][n]
  _Float16* logw = (_Float16*)(ws + ((size_t)6 << 20));    // 32 MB (total 38 MB)

  producers<<<2816, 256, 0, stream>>>(roi, Wq, bq, Wk, bk, Wc, pe, Wp, bp,
                                      qh, kh, kct, logw);
  attn_mfma<<<dim3(64, 16), 256, 0, stream>>>(qh, kh, logw, kct, bc, outp);
}

// Round 7
// 201.771 us; speedup vs baseline: 1.4505x; 1.4505x over previous
//
#include <hip/hip_runtime.h>

#define R_DIM 1024
#define N_DIM 1024
#define FEAT  1024
#define EMB   64
#define GROUP 16
#define DG    64

typedef _Float16 half8  __attribute__((ext_vector_type(8)));
typedef _Float16 half4v __attribute__((ext_vector_type(4)));
typedef float    f32x4  __attribute__((ext_vector_type(4)));

__device__ __forceinline__ half8 cvt8(const float* p) {
  const float4 a = *(const float4*)p;
  const float4 b = *(const float4*)(p + 4);
  half8 h;
  h[0] = (_Float16)a.x; h[1] = (_Float16)a.y; h[2] = (_Float16)a.z; h[3] = (_Float16)a.w;
  h[4] = (_Float16)b.x; h[5] = (_Float16)b.y; h[6] = (_Float16)b.z; h[7] = (_Float16)b.w;
  return h;
}

// ---------------------------------------------------------------------------
// K1 (R5-proven, ~4us): qh = f16(roi @ Wq^T + bq), kh = f16(roi @ Wk^T + bk)
// fp32 LDS-tiled 64x64, BK=16, register prefetch.
// ---------------------------------------------------------------------------
__global__ __launch_bounds__(256) void qk_gemm(
    const float* __restrict__ roi, const float* __restrict__ Wq,
    const float* __restrict__ bq,  const float* __restrict__ Wk,
    const float* __restrict__ bk,  _Float16* __restrict__ qh,
    _Float16* __restrict__ kh)
{
  __shared__ float aT[16][68];
  __shared__ float bqT[16][68];
  __shared__ float bkT[16][68];
  const int t  = threadIdx.x;
  const int r0 = blockIdx.x * 64, c0 = blockIdx.y * 64;
  const int lr = t >> 2, lk = (t & 3) << 2;
  const int ty = t >> 4, tx = t & 15;
  const float* ap  = roi + (r0 + lr) * FEAT + lk;
  const float* bqp = Wq  + (c0 + lr) * FEAT + lk;
  const float* bkp = Wk  + (c0 + lr) * FEAT + lk;
  float4 av  = *(const float4*)ap;
  float4 bqv = *(const float4*)bqp;
  float4 bkv = *(const float4*)bkp;
  float accq[4][4] = {}, acck[4][4] = {};
  for (int k0 = 0; k0 < FEAT; k0 += 16) {
    aT[lk+0][lr]=av.x;   aT[lk+1][lr]=av.y;   aT[lk+2][lr]=av.z;   aT[lk+3][lr]=av.w;
    bqT[lk+0][lr]=bqv.x; bqT[lk+1][lr]=bqv.y; bqT[lk+2][lr]=bqv.z; bqT[lk+3][lr]=bqv.w;
    bkT[lk+0][lr]=bkv.x; bkT[lk+1][lr]=bkv.y; bkT[lk+2][lr]=bkv.z; bkT[lk+3][lr]=bkv.w;
    __syncthreads();
    const bool more = (k0 + 16) < FEAT;
    float4 av_n, bqv_n, bkv_n;
    if (more) {
      av_n  = *(const float4*)(ap  + k0 + 16);
      bqv_n = *(const float4*)(bqp + k0 + 16);
      bkv_n = *(const float4*)(bkp + k0 + 16);
    }
#pragma unroll
    for (int kk = 0; kk < 16; ++kk) {
      const float4 a4 = *(const float4*)&aT[kk][ty << 2];
      const float4 q4 = *(const float4*)&bqT[kk][tx << 2];
      const float4 k4 = *(const float4*)&bkT[kk][tx << 2];
      const float ar[4] = {a4.x, a4.y, a4.z, a4.w};
      const float qr[4] = {q4.x, q4.y, q4.z, q4.w};
      const float kr[4] = {k4.x, k4.y, k4.z, k4.w};
#pragma unroll
      for (int i = 0; i < 4; ++i)
#pragma unroll
        for (int j = 0; j < 4; ++j) {
          accq[i][j] += ar[i] * qr[j];
          acck[i][j] += ar[i] * kr[j];
        }
    }
    __syncthreads();
    if (more) { av = av_n; bqv = bqv_n; bkv = bkv_n; }
  }
  const float4 bq4 = *(const float4*)(bq + c0 + (tx << 2));
  const float4 bk4 = *(const float4*)(bk + c0 + (tx << 2));
  const float bqr[4] = {bq4.x, bq4.y, bq4.z, bq4.w};
  const float bkr[4] = {bk4.x, bk4.y, bk4.z, bk4.w};
#pragma unroll
  for (int i = 0; i < 4; ++i) {
    half4v oq, ok;
#pragma unroll
    for (int j = 0; j < 4; ++j) {
      oq[j] = (_Float16)(accq[i][j] + bqr[j]);
      ok[j] = (_Float16)(acck[i][j] + bkr[j]);
    }
    const int row = r0 + (ty << 2) + i;
    *(half4v*)(qh + (size_t)row * FEAT + c0 + (tx << 2)) = oq;
    *(half4v*)(kh + (size_t)row * FEAT + c0 + (tx << 2)) = ok;
  }
}

// ---------------------------------------------------------------------------
// K2 NEW: pos as MFMA GEMM [R*N,64]x[64,16] in f16 (fp32 accum).
// Block = 128 rows of one r. Stage pe f32->f16 into XOR-swizzled LDS
// (byte ^= (row&7)<<4 -> conflict-free ds_read_b128 A-fragments).
// Wp fragment hoisted to registers. Epilogue log in regs -> LDS transpose
// tile -> coalesced 16B logw stores. No serial dep chains (R6 lesson).
// ---------------------------------------------------------------------------
__global__ __launch_bounds__(256) void pos_mfma(
    const float* __restrict__ pe, const float* __restrict__ Wp,
    const float* __restrict__ bp, _Float16* __restrict__ logw)
{
  __shared__ __align__(16) _Float16 Xs[128 * 64];   // 16 KB swizzled
  __shared__ __align__(16) _Float16 LW[16][136];    // 4.25 KB
  const int t  = threadIdx.x;
  const int bx = blockIdx.x;                        // 8192
  const int r  = bx >> 3;
  const int n0 = (bx & 7) << 7;
  const size_t gbase = ((size_t)bx << 13);          // 128 rows * 64 floats

  // stage: coalesced global float4 reads, swizzled f16 LDS writes
#pragma unroll
  for (int i = 0; i < 8; ++i) {
    const int flat4 = (i << 8) + t;                 // float4 index in 128x16
    const int row = flat4 >> 4, e4 = flat4 & 15;
    const float4 v = *(const float4*)(pe + gbase + ((size_t)flat4 << 2));
    half4v h;
    h[0] = (_Float16)v.x; h[1] = (_Float16)v.y;
    h[2] = (_Float16)v.z; h[3] = (_Float16)v.w;
    const int boff = (row << 7) + (((e4 << 3)) ^ ((row & 7) << 4));
    *(half4v*)((char*)Xs + boff) = h;
  }

  const int w = t >> 6, l = t & 63, q16 = l & 15, q4 = l >> 4;
  // Wp B-fragment: col g=q16, k = q4*8+j (and +32); bp per lane
  const float* wpp = Wp + (q16 << 6) + (q4 << 3);
  const half8 wb0 = cvt8(wpp);
  const half8 wb1 = cvt8(wpp + 32);
  const float bpg = bp[q16];
  __syncthreads();

#pragma unroll
  for (int tt = 0; tt < 2; ++tt) {
    const int lrbase = (w << 5) + (tt << 4);
    const int lr = lrbase + q16;
    const int b0 = (lr << 7) + (((q4 << 4))      ^ ((lr & 7) << 4));
    const int b1 = (lr << 7) + (((q4 << 4) + 64) ^ ((lr & 7) << 4));
    const half8 a0 = *(const half8*)((const char*)Xs + b0);
    const half8 a1 = *(const half8*)((const char*)Xs + b1);
    f32x4 acc = (f32x4){0.f, 0.f, 0.f, 0.f};
    acc = __builtin_amdgcn_mfma_f32_16x16x32_f16(a0, wb0, acc, 0, 0, 0);
    acc = __builtin_amdgcn_mfma_f32_16x16x32_f16(a1, wb1, acc, 0, 0, 0);
    half4v o;
#pragma unroll
    for (int j = 0; j < 4; ++j) {
      const float v = fmaxf(acc[j] + bpg, 1e-6f);   // relu+clip
      o[j] = (_Float16)__logf(v);
    }
    // D: col=g (q16), rows = lrbase + q4*4 + j  (consecutive j)
    *(half4v*)&LW[q16][lrbase + (q4 << 2)] = o;
  }
  __syncthreads();

  // coalesced out: thread t -> g=t>>4, 8-f16 chunk n4=t&15
  const int g = t >> 4, n4 = t & 15;
  const half8 vv = *(const half8*)&LW[g][n4 << 3];
  *(half8*)(logw + ((size_t)((r << 4) + g) << 10) + n0 + (n4 << 3)) = vv;
}

// ---------------------------------------------------------------------------
// K3 (R5-proven, ~4us): kct[g][o][n] = f16( sum_f Wc[g][o][f] * roi[n][f] )
// ---------------------------------------------------------------------------
__global__ __launch_bounds__(256) void kc_gemm(
    const float* __restrict__ roi, const float* __restrict__ Wc,
    _Float16* __restrict__ kct)
{
  __shared__ float aT[16][68];
  __shared__ float bT[16][68];
  const int t  = threadIdx.x;
  const int n0 = blockIdx.x * 64;
  const int g  = blockIdx.y;
  const int lr = t >> 2, lk = (t & 3) << 2;
  const int ty = t >> 4, tx = t & 15;
  const float* ap  = Wc  + (size_t)(g * DG + lr) * FEAT + lk;
  const float* bp_ = roi + (size_t)(n0 + lr) * FEAT + lk;
  float4 av = *(const float4*)ap;
  float4 bv = *(const float4*)bp_;
  float acc[4][4] = {};
  for (int k0 = 0; k0 < FEAT; k0 += 16) {
    aT[lk+0][lr]=av.x; aT[lk+1][lr]=av.y; aT[lk+2][lr]=av.z; aT[lk+3][lr]=av.w;
    bT[lk+0][lr]=bv.x; bT[lk+1][lr]=bv.y; bT[lk+2][lr]=bv.z; bT[lk+3][lr]=bv.w;
    __syncthreads();
    const bool more = (k0 + 16) < FEAT;
    float4 av_n, bv_n;
    if (more) {
      av_n = *(const float4*)(ap  + k0 + 16);
      bv_n = *(const float4*)(bp_ + k0 + 16);
    }
#pragma unroll
    for (int kk = 0; kk < 16; ++kk) {
      const float4 a4 = *(const float4*)&aT[kk][ty << 2];
      const float4 b4 = *(const float4*)&bT[kk][tx << 2];
      const float ar[4] = {a4.x, a4.y, a4.z, a4.w};
      const float br[4] = {b4.x, b4.y, b4.z, b4.w};
#pragma unroll
      for (int i = 0; i < 4; ++i)
#pragma unroll
        for (int j = 0; j < 4; ++j) acc[i][j] += ar[i] * br[j];
    }
    __syncthreads();
    if (more) { av = av_n; bv = bv_n; }
  }
#pragma unroll
  for (int i = 0; i < 4; ++i) {
    half4v o4;
#pragma unroll
    for (int j = 0; j < 4; ++j) o4[j] = (_Float16)acc[i][j];
    *(half4v*)(kct + (size_t)((g << 6) + (ty << 2) + i) * N_DIM + n0 + (tx << 2)) = o4;
  }
}

// ---------------------------------------------------------------------------
// K4 (unchanged): MFMA attention. Block = 16 q-rows x one g, 4 waves.
// ---------------------------------------------------------------------------
#define PLD 1032
__global__ __launch_bounds__(256) void attn_mfma(
    const _Float16* __restrict__ qh, const _Float16* __restrict__ kh,
    const _Float16* __restrict__ logw, const _Float16* __restrict__ kct,
    const float* __restrict__ bc, float* __restrict__ outp)
{
  __shared__ __align__(16) _Float16 P[16][PLD];
  __shared__ float Ored[4][16][68];
  __shared__ float redm[4][16];
  __shared__ float redl[4][16];

  const int t   = threadIdx.x;
  const int w   = t >> 6;
  const int l   = t & 63;
  const int q16 = l & 15;
  const int q4  = l >> 4;
  const int g   = blockIdx.y;
  const int r0  = blockIdx.x << 4;
  const int nbase = w << 8;

  const half8* qp = (const half8*)(qh + (size_t)(r0 + q16) * FEAT + (g << 6) + (q4 << 3));
  const half8 a0 = qp[0];
  const half8 a1 = qp[4];

  f32x4 S[16];
#pragma unroll
  for (int i = 0; i < 16; ++i) S[i] = (f32x4){0.f, 0.f, 0.f, 0.f};
#pragma unroll
  for (int t16 = 0; t16 < 16; ++t16) {
    const int n0 = nbase + (t16 << 4);
    const half8* kp = (const half8*)(kh + (size_t)(n0 + q16) * FEAT + (g << 6) + (q4 << 3));
    S[t16] = __builtin_amdgcn_mfma_f32_16x16x32_f16(a0, kp[0], S[t16], 0, 0, 0);
    S[t16] = __builtin_amdgcn_mfma_f32_16x16x32_f16(a1, kp[4], S[t16], 0, 0, 0);
  }

#pragma unroll
  for (int t16 = 0; t16 < 16; ++t16) {
    const int n = nbase + (t16 << 4) + q16;
#pragma unroll
    for (int j = 0; j < 4; ++j) {
      const int r = r0 + (q4 << 2) + j;
      const float lw = (float)logw[(size_t)(((r << 4) + g) << 10) + n];
      S[t16][j] = S[t16][j] * 0.125f + lw;
    }
  }

  float m[4] = {-1e30f, -1e30f, -1e30f, -1e30f};
#pragma unroll
  for (int t16 = 0; t16 < 16; ++t16)
#pragma unroll
    for (int j = 0; j < 4; ++j) m[j] = fmaxf(m[j], S[t16][j]);
#pragma unroll
  for (int off = 8; off; off >>= 1)
#pragma unroll
    for (int j = 0; j < 4; ++j) m[j] = fmaxf(m[j], __shfl_xor(m[j], off));
  if (q16 == 0) {
#pragma unroll
    for (int j = 0; j < 4; ++j) redm[w][(q4 << 2) + j] = m[j];
  }
  __syncthreads();
#pragma unroll
  for (int j = 0; j < 4; ++j) {
    const int r = (q4 << 2) + j;
    m[j] = fmaxf(fmaxf(redm[0][r], redm[1][r]), fmaxf(redm[2][r], redm[3][r]));
  }

  float ls[4] = {0.f, 0.f, 0.f, 0.f};
#pragma unroll
  for (int t16 = 0; t16 < 16; ++t16) {
    const int n = nbase + (t16 << 4) + q16;
#pragma unroll
    for (int j = 0; j < 4; ++j) {
      const float p = __expf(S[t16][j] - m[j]);
      ls[j] += p;
      P[(q4 << 2) + j][n] = (_Float16)p;
    }
  }
#pragma unroll
  for (int off = 8; off; off >>= 1)
#pragma unroll
    for (int j = 0; j < 4; ++j) ls[j] += __shfl_xor(ls[j], off);
  if (q16 == 0) {
#pragma unroll
    for (int j = 0; j < 4; ++j) redl[w][(q4 << 2) + j] = ls[j];
  }
  __syncthreads();

  f32x4 O[4];
#pragma unroll
  for (int ot = 0; ot < 4; ++ot) O[ot] = (f32x4){0.f, 0.f, 0.f, 0.f};
#pragma unroll
  for (int ks = 0; ks < 8; ++ks) {
    const int nk = nbase + (ks << 5) + (q4 << 3);
    const half8 pa = *(const half8*)&P[q16][nk];
#pragma unroll
    for (int ot = 0; ot < 4; ++ot) {
      const half8 bfr = *(const half8*)(kct + (size_t)((g << 6) + (ot << 4) + q16) * N_DIM + nk);
      O[ot] = __builtin_amdgcn_mfma_f32_16x16x32_f16(pa, bfr, O[ot], 0, 0, 0);
    }
  }
#pragma unroll
  for (int ot = 0; ot < 4; ++ot)
#pragma unroll
    for (int j = 0; j < 4; ++j)
      Ored[w][(q4 << 2) + j][(ot << 4) + q16] = O[ot][j];
  __syncthreads();

  const int r  = t >> 4;
  const int o0 = (t & 15) << 2;
  const float lsum = redl[0][r] + redl[1][r] + redl[2][r] + redl[3][r];
  const float inv  = 1.0f / lsum;
  float o[4];
#pragma unroll
  for (int c = 0; c < 4; ++c)
    o[c] = Ored[0][r][o0 + c] + Ored[1][r][o0 + c] + Ored[2][r][o0 + c] + Ored[3][r][o0 + c];
  const float4 bcv = *(const float4*)(bc + (g << 6) + o0);
  float4 res;
  res.x = o[0] * inv + bcv.x;
  res.y = o[1] * inv + bcv.y;
  res.z = o[2] * inv + bcv.z;
  res.w = o[3] * inv + bcv.w;
  *(float4*)(outp + (size_t)(r0 + r) * FEAT + (g << 6) + o0) = res;
}

// ---------------------------------------------------------------------------
extern "C" void kernel_launch(void* const* d_in, const int* in_sizes, int n_in,
                              void* d_out, int out_size, void* d_ws, size_t ws_size,
                              hipStream_t stream)
{
  const float* pe  = (const float*)d_in[0];
  const float* roi = (const float*)d_in[1];
  const float* Wq  = (const float*)d_in[2];
  const float* bq  = (const float*)d_in[3];
  const float* Wk  = (const float*)d_in[4];
  const float* bk  = (const float*)d_in[5];
  const float* Wp  = (const float*)d_in[6];
  const float* bp  = (const float*)d_in[7];
  const float* Wc  = (const float*)d_in[8];
  const float* bc  = (const float*)d_in[9];
  float* outp = (float*)d_out;

  char* ws = (char*)d_ws;
  _Float16* qh   = (_Float16*)(ws);                        // 2 MB
  _Float16* kh   = (_Float16*)(ws + ((size_t)2 << 20));    // 2 MB
  _Float16* kct  = (_Float16*)(ws + ((size_t)4 << 20));    // 2 MB [g][o][n]
  _Float16* logw = (_Float16*)(ws + ((size_t)6 << 20));    // 32 MB (total 38 MB)

  qk_gemm<<<dim3(16, 16), 256, 0, stream>>>(roi, Wq, bq, Wk, bk, qh, kh);
  pos_mfma<<<8192, 256, 0, stream>>>(pe, Wp, bp, logw);
  kc_gemm<<<dim3(16, 16), 256, 0, stream>>>(roi, Wc, kct);
  attn_mfma<<<dim3(64, 16), 256, 0, stream>>>(qh, kh, logw, kct, bc, outp);
}

// Round 8
// 190.395 us; speedup vs baseline: 1.5371x; 1.0598x over previous
//
#include <hip/hip_runtime.h>

#define R_DIM 1024
#define N_DIM 1024
#define FEAT  1024
#define EMB   64
#define GROUP 16
#define DG    64

typedef _Float16 half8  __attribute__((ext_vector_type(8)));
typedef _Float16 half4v __attribute__((ext_vector_type(4)));
typedef float    f32x4  __attribute__((ext_vector_type(4)));

__device__ __forceinline__ half8 cvt8(const float* p) {
  const float4 a = *(const float4*)p;
  const float4 b = *(const float4*)(p + 4);
  half8 h;
  h[0] = (_Float16)a.x; h[1] = (_Float16)a.y; h[2] = (_Float16)a.z; h[3] = (_Float16)a.w;
  h[4] = (_Float16)b.x; h[5] = (_Float16)b.y; h[6] = (_Float16)b.z; h[7] = (_Float16)b.w;
  return h;
}

// ---------------------------------------------------------------------------
// K1: qh = f16(roi @ Wq^T + bq) row-major; k stored 8-interleaved:
// khI[g][e>>3][n][e&7]  (so attn QK B-fragment loads are lane-coalesced).
// ---------------------------------------------------------------------------
__global__ __launch_bounds__(256) void qk_gemm(
    const float* __restrict__ roi, const float* __restrict__ Wq,
    const float* __restrict__ bq,  const float* __restrict__ Wk,
    const float* __restrict__ bk,  _Float16* __restrict__ qh,
    _Float16* __restrict__ khI)
{
  __shared__ float aT[16][68];
  __shared__ float bqT[16][68];
  __shared__ float bkT[16][68];
  const int t  = threadIdx.x;
  const int r0 = blockIdx.x * 64, c0 = blockIdx.y * 64;
  const int lr = t >> 2, lk = (t & 3) << 2;
  const int ty = t >> 4, tx = t & 15;
  const float* ap  = roi + (r0 + lr) * FEAT + lk;
  const float* bqp = Wq  + (c0 + lr) * FEAT + lk;
  const float* bkp = Wk  + (c0 + lr) * FEAT + lk;
  float4 av  = *(const float4*)ap;
  float4 bqv = *(const float4*)bqp;
  float4 bkv = *(const float4*)bkp;
  float accq[4][4] = {}, acck[4][4] = {};
  for (int k0 = 0; k0 < FEAT; k0 += 16) {
    aT[lk+0][lr]=av.x;   aT[lk+1][lr]=av.y;   aT[lk+2][lr]=av.z;   aT[lk+3][lr]=av.w;
    bqT[lk+0][lr]=bqv.x; bqT[lk+1][lr]=bqv.y; bqT[lk+2][lr]=bqv.z; bqT[lk+3][lr]=bqv.w;
    bkT[lk+0][lr]=bkv.x; bkT[lk+1][lr]=bkv.y; bkT[lk+2][lr]=bkv.z; bkT[lk+3][lr]=bkv.w;
    __syncthreads();
    const bool more = (k0 + 16) < FEAT;
    float4 av_n, bqv_n, bkv_n;
    if (more) {
      av_n  = *(const float4*)(ap  + k0 + 16);
      bqv_n = *(const float4*)(bqp + k0 + 16);
      bkv_n = *(const float4*)(bkp + k0 + 16);
    }
#pragma unroll
    for (int kk = 0; kk < 16; ++kk) {
      const float4 a4 = *(const float4*)&aT[kk][ty << 2];
      const float4 q4 = *(const float4*)&bqT[kk][tx << 2];
      const float4 k4 = *(const float4*)&bkT[kk][tx << 2];
      const float ar[4] = {a4.x, a4.y, a4.z, a4.w};
      const float qr[4] = {q4.x, q4.y, q4.z, q4.w};
      const float kr[4] = {k4.x, k4.y, k4.z, k4.w};
#pragma unroll
      for (int i = 0; i < 4; ++i)
#pragma unroll
        for (int j = 0; j < 4; ++j) {
          accq[i][j] += ar[i] * qr[j];
          acck[i][j] += ar[i] * kr[j];
        }
    }
    __syncthreads();
    if (more) { av = av_n; bqv = bqv_n; bkv = bkv_n; }
  }
  const float4 bq4 = *(const float4*)(bq + c0 + (tx << 2));
  const float4 bk4 = *(const float4*)(bk + c0 + (tx << 2));
  const float bqr[4] = {bq4.x, bq4.y, bq4.z, bq4.w};
  const float bkr[4] = {bk4.x, bk4.y, bk4.z, bk4.w};
  const int g  = c0 >> 6;          // e = tx*4+j  (c0 is a multiple of 64)
#pragma unroll
  for (int i = 0; i < 4; ++i) {
    half4v oq, ok;
#pragma unroll
    for (int j = 0; j < 4; ++j) {
      oq[j] = (_Float16)(accq[i][j] + bqr[j]);
      ok[j] = (_Float16)(acck[i][j] + bkr[j]);
    }
    const int row = r0 + (ty << 2) + i;   // n
    *(half4v*)(qh + (size_t)row * FEAT + c0 + (tx << 2)) = oq;
    // khI idx = ((g*8 + e>>3)<<13) + (n<<3) + (e&7); e>>3 = tx>>1, e&7 base = 4*(tx&1)
    *(half4v*)(khI + ((((size_t)g << 3) + (tx >> 1)) << 13) + (row << 3) + ((tx & 1) << 2)) = ok;
  }
}

// ---------------------------------------------------------------------------
// K2 v2: pos as MFMA GEMM, register-double-buffered 4 tiles/block (R7 lesson:
// per-iter load->cvt->ds_write kept only ~1 load in flight; now all 8 loads
// of tile t+1 are issued before tile t's compute, 8KB/wave in flight).
// ---------------------------------------------------------------------------
__global__ __launch_bounds__(256) void pos_mfma(
    const float* __restrict__ pe, const float* __restrict__ Wp,
    const float* __restrict__ bp, _Float16* __restrict__ logw)
{
  __shared__ __align__(16) _Float16 Xs[128 * 64];   // 16 KB swizzled
  __shared__ __align__(16) _Float16 LW[16][136];    // 4.25 KB
  const int t  = threadIdx.x;
  const int bx = blockIdx.x;                        // 2048 blocks x 4 tiles
  const int w = t >> 6, l = t & 63, q16 = l & 15, q4 = l >> 4;

  const float* wpp = Wp + (q16 << 6) + (q4 << 3);
  const half8 wb0 = cvt8(wpp);
  const half8 wb1 = cvt8(wpp + 32);
  const float bpg = bp[q16];

  const size_t base = ((size_t)bx) << 15;           // 4*128 rows * 64 floats
  float4 cur[8], nxt[8];
#pragma unroll
  for (int i = 0; i < 8; ++i)
    cur[i] = *(const float4*)(pe + base + ((size_t)((i << 8) + t) << 2));

  for (int tt = 0; tt < 4; ++tt) {
    if (tt < 3) {
#pragma unroll
      for (int i = 0; i < 8; ++i)
        nxt[i] = *(const float4*)(pe + base + ((size_t)(((tt + 1) << 11) + (i << 8) + t) << 2));
    }
    // cvt + swizzled LDS write of cur
#pragma unroll
    for (int i = 0; i < 8; ++i) {
      const int flat4 = (i << 8) + t;
      const int row = flat4 >> 4, e4 = flat4 & 15;
      half4v h;
      h[0] = (_Float16)cur[i].x; h[1] = (_Float16)cur[i].y;
      h[2] = (_Float16)cur[i].z; h[3] = (_Float16)cur[i].w;
      const int boff = (row << 7) + ((e4 << 3) ^ ((row & 7) << 4));
      *(half4v*)((char*)Xs + boff) = h;
    }
    __syncthreads();                                 // A
#pragma unroll
    for (int sub = 0; sub < 2; ++sub) {
      const int lrbase = (w << 5) + (sub << 4);
      const int lrr = lrbase + q16;
      const int b0 = (lrr << 7) + (((q4 << 4))      ^ ((lrr & 7) << 4));
      const int b1 = (lrr << 7) + (((q4 << 4) + 64) ^ ((lrr & 7) << 4));
      const half8 a0 = *(const half8*)((const char*)Xs + b0);
      const half8 a1 = *(const half8*)((const char*)Xs + b1);
      f32x4 acc = (f32x4){0.f, 0.f, 0.f, 0.f};
      acc = __builtin_amdgcn_mfma_f32_16x16x32_f16(a0, wb0, acc, 0, 0, 0);
      acc = __builtin_amdgcn_mfma_f32_16x16x32_f16(a1, wb1, acc, 0, 0, 0);
      half4v o;
#pragma unroll
      for (int j = 0; j < 4; ++j) {
        const float v = fmaxf(acc[j] + bpg, 1e-6f);
        o[j] = (_Float16)__logf(v);
      }
      *(half4v*)&LW[q16][lrbase + (q4 << 2)] = o;
    }
    __syncthreads();                                 // B
    const int rowblk = (bx << 2) + tt;               // global 128-row tile
    const int r = rowblk >> 3, n0 = (rowblk & 7) << 7;
    const int gg = t >> 4, n4 = t & 15;
    const half8 vv = *(const half8*)&LW[gg][n4 << 3];
    *(half8*)(logw + ((size_t)((r << 4) + gg) << 10) + n0 + (n4 << 3)) = vv;
    if (tt < 3) {
#pragma unroll
      for (int i = 0; i < 8; ++i) cur[i] = nxt[i];
    }
  }
}

// ---------------------------------------------------------------------------
// K3: kc stored 8-interleaved: kctI[g][n>>3][o][n&7]  (lane-coalesced PV B).
// ---------------------------------------------------------------------------
__global__ __launch_bounds__(256) void kc_gemm(
    const float* __restrict__ roi, const float* __restrict__ Wc,
    _Float16* __restrict__ kctI)
{
  __shared__ float aT[16][68];
  __shared__ float bT[16][68];
  const int t   = threadIdx.x;
  const int n0g = blockIdx.x * 64;
  const int g   = blockIdx.y;
  const int lr = t >> 2, lk = (t & 3) << 2;
  const int ty = t >> 4, tx = t & 15;
  const float* ap  = Wc  + (size_t)(g * DG + lr) * FEAT + lk;
  const float* bp_ = roi + (size_t)(n0g + lr) * FEAT + lk;
  float4 av = *(const float4*)ap;
  float4 bv = *(const float4*)bp_;
  float acc[4][4] = {};
  for (int k0 = 0; k0 < FEAT; k0 += 16) {
    aT[lk+0][lr]=av.x; aT[lk+1][lr]=av.y; aT[lk+2][lr]=av.z; aT[lk+3][lr]=av.w;
    bT[lk+0][lr]=bv.x; bT[lk+1][lr]=bv.y; bT[lk+2][lr]=bv.z; bT[lk+3][lr]=bv.w;
    __syncthreads();
    const bool more = (k0 + 16) < FEAT;
    float4 av_n, bv_n;
    if (more) {
      av_n = *(const float4*)(ap  + k0 + 16);
      bv_n = *(const float4*)(bp_ + k0 + 16);
    }
#pragma unroll
    for (int kk = 0; kk < 16; ++kk) {
      const float4 a4 = *(const float4*)&aT[kk][ty << 2];
      const float4 b4 = *(const float4*)&bT[kk][tx << 2];
      const float ar[4] = {a4.x, a4.y, a4.z, a4.w};
      const float br[4] = {b4.x, b4.y, b4.z, b4.w};
#pragma unroll
      for (int i = 0; i < 4; ++i)
#pragma unroll
        for (int j = 0; j < 4; ++j) acc[i][j] += ar[i] * br[j];
    }
    __syncthreads();
    if (more) { av = av_n; bv = bv_n; }
  }
  // o = ty*4+i, n = n0g+tx*4+j ; kctI idx = ((g*128 + n>>3)<<9) + (o<<3) + (n&7)
#pragma unroll
  for (int i = 0; i < 4; ++i) {
    half4v o4;
#pragma unroll
    for (int j = 0; j < 4; ++j) o4[j] = (_Float16)acc[i][j];
    *(half4v*)(kctI + ((((size_t)g << 7) + ((n0g + (tx << 2)) >> 3)) << 9)
               + (((ty << 2) + i) << 3) + ((tx & 1) << 2)) = o4;
  }
}

// ---------------------------------------------------------------------------
// K4: MFMA attention. 1D grid 1024, XCD swizzle: bid%8 == g&7 so all 64
// blocks of a g share one XCD's L2 (khI/kctI g-slices stay resident).
// khI/kctI reads are lane-coalesced (256B segments per quarter-wave).
// ---------------------------------------------------------------------------
__global__ __launch_bounds__(256) void attn_mfma(
    const _Float16* __restrict__ qh, const _Float16* __restrict__ khI,
    const _Float16* __restrict__ logw, const _Float16* __restrict__ kctI,
    const float* __restrict__ bc, float* __restrict__ outp)
{
  __shared__ float Ored[4][16][68];
  __shared__ float redm[4][16];
  __shared__ float redl[4][16];
#define PLD 1032
  __shared__ __align__(16) _Float16 P[16][PLD];

  const int t   = threadIdx.x;
  const int w   = t >> 6;
  const int l   = t & 63;
  const int q16 = l & 15;
  const int q4  = l >> 4;
  const int bid = blockIdx.x;
  const int g   = (bid & 7) + ((bid >> 9) << 3);
  const int r0  = ((bid >> 3) & 63) << 4;
  const int nbase = w << 8;

  const half8* qp = (const half8*)(qh + (size_t)(r0 + q16) * FEAT + (g << 6) + (q4 << 3));
  const half8 a0 = qp[0];
  const half8 a1 = qp[4];

  const _Float16* kbase = khI  + ((size_t)g << 16);
  const _Float16* cbase = kctI + ((size_t)g << 16);

  f32x4 S[16];
#pragma unroll
  for (int i = 0; i < 16; ++i) S[i] = (f32x4){0.f, 0.f, 0.f, 0.f};
#pragma unroll
  for (int t16 = 0; t16 < 16; ++t16) {
    const int n = nbase + (t16 << 4) + q16;
    const half8 k0 = *(const half8*)(kbase + ((size_t)q4 << 13) + (n << 3));
    const half8 k1 = *(const half8*)(kbase + ((size_t)(4 + q4) << 13) + (n << 3));
    S[t16] = __builtin_amdgcn_mfma_f32_16x16x32_f16(a0, k0, S[t16], 0, 0, 0);
    S[t16] = __builtin_amdgcn_mfma_f32_16x16x32_f16(a1, k1, S[t16], 0, 0, 0);
  }

#pragma unroll
  for (int t16 = 0; t16 < 16; ++t16) {
    const int n = nbase + (t16 << 4) + q16;
#pragma unroll
    for (int j = 0; j < 4; ++j) {
      const int r = r0 + (q4 << 2) + j;
      const float lw = (float)logw[(size_t)(((r << 4) + g) << 10) + n];
      S[t16][j] = S[t16][j] * 0.125f + lw;
    }
  }

  float m[4] = {-1e30f, -1e30f, -1e30f, -1e30f};
#pragma unroll
  for (int t16 = 0; t16 < 16; ++t16)
#pragma unroll
    for (int j = 0; j < 4; ++j) m[j] = fmaxf(m[j], S[t16][j]);
#pragma unroll
  for (int off = 8; off; off >>= 1)
#pragma unroll
    for (int j = 0; j < 4; ++j) m[j] = fmaxf(m[j], __shfl_xor(m[j], off));
  if (q16 == 0) {
#pragma unroll
    for (int j = 0; j < 4; ++j) redm[w][(q4 << 2) + j] = m[j];
  }
  __syncthreads();
#pragma unroll
  for (int j = 0; j < 4; ++j) {
    const int r = (q4 << 2) + j;
    m[j] = fmaxf(fmaxf(redm[0][r], redm[1][r]), fmaxf(redm[2][r], redm[3][r]));
  }

  float ls[4] = {0.f, 0.f, 0.f, 0.f};
#pragma unroll
  for (int t16 = 0; t16 < 16; ++t16) {
    const int n = nbase + (t16 << 4) + q16;
#pragma unroll
    for (int j = 0; j < 4; ++j) {
      const float p = __expf(S[t16][j] - m[j]);
      ls[j] += p;
      P[(q4 << 2) + j][n] = (_Float16)p;
    }
  }
#pragma unroll
  for (int off = 8; off; off >>= 1)
#pragma unroll
    for (int j = 0; j < 4; ++j) ls[j] += __shfl_xor(ls[j], off);
  if (q16 == 0) {
#pragma unroll
    for (int j = 0; j < 4; ++j) redl[w][(q4 << 2) + j] = ls[j];
  }
  __syncthreads();

  f32x4 O[4];
#pragma unroll
  for (int ot = 0; ot < 4; ++ot) O[ot] = (f32x4){0.f, 0.f, 0.f, 0.f};
#pragma unroll
  for (int ks = 0; ks < 8; ++ks) {
    const int nk = nbase + (ks << 5) + (q4 << 3);
    const half8 pa = *(const half8*)&P[q16][nk];
#pragma unroll
    for (int ot = 0; ot < 4; ++ot) {
      const half8 bfr = *(const half8*)(cbase + ((size_t)(nk >> 3) << 9) + (((ot << 4) + q16) << 3));
      O[ot] = __builtin_amdgcn_mfma_f32_16x16x32_f16(pa, bfr, O[ot], 0, 0, 0);
    }
  }
#pragma unroll
  for (int ot = 0; ot < 4; ++ot)
#pragma unroll
    for (int j = 0; j < 4; ++j)
      Ored[w][(q4 << 2) + j][(ot << 4) + q16] = O[ot][j];
  __syncthreads();

  const int r  = t >> 4;
  const int o0 = (t & 15) << 2;
  const float lsum = redl[0][r] + redl[1][r] + redl[2][r] + redl[3][r];
  const float inv  = 1.0f / lsum;
  float o[4];
#pragma unroll
  for (int c = 0; c < 4; ++c)
    o[c] = Ored[0][r][o0 + c] + Ored[1][r][o0 + c] + Ored[2][r][o0 + c] + Ored[3][r][o0 + c];
  const float4 bcv = *(const float4*)(bc + (g << 6) + o0);
  float4 res;
  res.x = o[0] * inv + bcv.x;
  res.y = o[1] * inv + bcv.y;
  res.z = o[2] * inv + bcv.z;
  res.w = o[3] * inv + bcv.w;
  *(float4*)(outp + (size_t)(r0 + r) * FEAT + (g << 6) + o0) = res;
}

// ---------------------------------------------------------------------------
extern "C" void kernel_launch(void* const* d_in, const int* in_sizes, int n_in,
                              void* d_out, int out_size, void* d_ws, size_t ws_size,
                              hipStream_t stream)
{
  const float* pe  = (const float*)d_in[0];
  const float* roi = (const float*)d_in[1];
  const float* Wq  = (const float*)d_in[2];
  const float* bq  = (const float*)d_in[3];
  const float* Wk  = (const float*)d_in[4];
  const float* bk  = (const float*)d_in[5];
  const float* Wp  = (const float*)d_in[6];
  const float* bp  = (const float*)d_in[7];
  const float* Wc  = (const float*)d_in[8];
  const float* bc  = (const float*)d_in[9];
  float* outp = (float*)d_out;

  char* ws = (char*)d_ws;
  _Float16* qh   = (_Float16*)(ws);                        // 2 MB
  _Float16* khI  = (_Float16*)(ws + ((size_t)2 << 20));    // 2 MB [g][e/8][n][e%8]
  _Float16* kctI = (_Float16*)(ws + ((size_t)4 << 20));    // 2 MB [g][n/8][o][n%8]
  _Float16* logw = (_Float16*)(ws + ((size_t)6 << 20));    // 32 MB (total 38 MB)

  qk_gemm<<<dim3(16, 16), 256, 0, stream>>>(roi, Wq, bq, Wk, bk, qh, khI);
  pos_mfma<<<2048, 256, 0, stream>>>(pe, Wp, bp, logw);
  kc_gemm<<<dim3(16, 16), 256, 0, stream>>>(roi, Wc, kctI);
  attn_mfma<<<1024, 256, 0, stream>>>(qh, khI, logw, kctI, bc, outp);
}